// Round 3
// baseline (3880.015 us; speedup 1.0000x reference)
//
#include <hip/hip_runtime.h>
#include <cstdint>
#include <cstddef>

#define NS    8192
#define HDIM  1024
#define B0DIM 64
#define FDIM  2048
#define ODIM  2048
#define NBLK  6
#define XCOLS (HDIM + B0DIM + FDIM)   // 3136

typedef __bf16 bf16_t;
typedef __bf16 bf16x8 __attribute__((ext_vector_type(8)));
typedef float  f32x4  __attribute__((ext_vector_type(4)));

static const size_t NF = (size_t)NS * FDIM;   // 16,777,216
static const size_t NH = (size_t)NS * HDIM;   //  8,388,608
static const size_t XE = (size_t)NS * XCOLS;  // 25,690,112

__device__ inline bf16x8 cvt8(f32x4 lo, f32x4 hi) {
  bf16x8 r;
#pragma unroll
  for (int i = 0; i < 4; ++i) { r[i] = (bf16_t)lo[i]; r[i + 4] = (bf16_t)hi[i]; }
  return r;
}

__device__ inline void gload_lds16(const bf16_t* g, bf16_t* l) {
  __builtin_amdgcn_global_load_lds(
      (const __attribute__((address_space(1))) void*)g,
      (__attribute__((address_space(3))) void*)l, 16, 0, 0);
}

// ------------------------------------------------------------------
// fp32 -> bf16 bulk conversion (n multiple of 2048)
// ------------------------------------------------------------------
__global__ __launch_bounds__(256) void cvt_w(const float* __restrict__ in,
                                             bf16_t* __restrict__ out) {
  size_t i = ((size_t)blockIdx.x * 256 + threadIdx.x) << 3;
  f32x4 lo = *(const f32x4*)(in + i);
  f32x4 hi = *(const f32x4*)(in + i + 4);
  *(bf16x8*)(out + i) = cvt8(lo, hi);
}

// q = pi/4 * d^2  (d = x[:, H+B0:], fp32 in; round d to bf16 first)
__global__ __launch_bounds__(256) void ew_qinit(const float* __restrict__ x,
                                                bf16_t* __restrict__ q) {
  int t = blockIdx.x * 256 + threadIdx.x;
  int n = t >> 8;
  int j = (t & 255) << 3;
  const float* p = x + (size_t)n * XCOLS + (HDIM + B0DIM) + j;
  f32x4 lo = *(const f32x4*)p;
  f32x4 hi = *(const f32x4*)(p + 4);
  bf16x8 o;
#pragma unroll
  for (int i = 0; i < 4; ++i) {
    float a = (float)(bf16_t)lo[i];
    float b = (float)(bf16_t)hi[i];
    o[i]     = (bf16_t)(0.7853981633974483f * a * a);
    o[i + 4] = (bf16_t)(0.7853981633974483f * b * b);
  }
  *(bf16x8*)(q + (size_t)n * FDIM + j) = o;
}

__global__ __launch_bounds__(256) void ew_mul(const bf16_t* a, const bf16_t* b,
                                              bf16_t* o) {
  size_t i = (size_t)(blockIdx.x * 256 + threadIdx.x) << 3;
  bf16x8 va = *(const bf16x8*)(a + i);
  bf16x8 vb = *(const bf16x8*)(b + i);
  bf16x8 vo;
#pragma unroll
  for (int k = 0; k < 8; ++k) vo[k] = (bf16_t)((float)va[k] * (float)vb[k]);
  *(bf16x8*)(o + i) = vo;
}

// ------------------------------------------------------------------
// NT GEMM, all-bf16 operands, global_load_lds width-16 staging (m97).
// C[n][m] = epi( sum_k A[n][k]*W[m][k] + bias[m] )
// 128x128 tile, 4 waves, wave = 64x64 via 4x4 mfma_f32_16x16x32_bf16.
// EPI: 0 none | 1 relu | 2 C+= | 3 aqhid: C=v, out2=C*(x1+x2)
//      4 ufuse: C=(relu(v)+x1+x2)*x3 | 5 qupd: qn=C-leaky(v), C=qn, out2=qn*x1
// ------------------------------------------------------------------
template <int EPI, bool OUTF32>
__global__ __launch_bounds__(256) void gemm_nt(
    const bf16_t* __restrict__ A, int lda, const bf16_t* __restrict__ W, int K,
    const float* __restrict__ bias, void* Cv, int ldc,
    const bf16_t* __restrict__ x1, const bf16_t* __restrict__ x2,
    const bf16_t* __restrict__ x3, bf16_t* __restrict__ out2,
    const float* __restrict__ alpha_p) {
  __shared__ __align__(16) bf16_t As[128 * 32];
  __shared__ __align__(16) bf16_t Bs[128 * 32];

  const int tid  = threadIdx.x;
  const int lane = tid & 63;
  const int wave = tid >> 6;
  const int wm   = wave & 1;
  const int wn   = wave >> 1;
  const int row0 = blockIdx.y * 128;
  const int col0 = blockIdx.x * 128;

  // staging: thread t -> row (t>>2) [and +64], 16B k-chunk (t&3)
  const int srow  = tid >> 2;
  const int spart = tid & 3;

  const bf16_t* Ag  = A + (size_t)(row0 + srow) * lda + spart * 8;
  const bf16_t* Ag2 = Ag + (size_t)64 * lda;
  const bf16_t* Wg  = W + (size_t)(col0 + srow) * K + spart * 8;
  const bf16_t* Wg2 = Wg + (size_t)64 * K;

  // wave-uniform LDS bases; HW scatters lane l at base + l*16B
  bf16_t* AsB0 = &As[wave * 512];
  bf16_t* AsB1 = &As[2048 + wave * 512];
  bf16_t* BsB0 = &Bs[wave * 512];
  bf16_t* BsB1 = &Bs[2048 + wave * 512];

  f32x4 acc[4][4];
#pragma unroll
  for (int i = 0; i < 4; ++i)
#pragma unroll
    for (int j = 0; j < 4; ++j)
#pragma unroll
      for (int r = 0; r < 4; ++r) acc[i][j][r] = 0.0f;

  const int fr   = lane & 15;
  const int quad = lane >> 4;
  const int nk   = K >> 5;

  for (int kt = 0; kt < nk; ++kt) {
    const int ko = kt * 32;
    __syncthreads();
    gload_lds16(Ag + ko, AsB0);
    gload_lds16(Ag2 + ko, AsB1);
    gload_lds16(Wg + ko, BsB0);
    gload_lds16(Wg2 + ko, BsB1);
    __syncthreads();   // drains vmcnt -> LDS visible

    bf16x8 af[4], bfr[4];
#pragma unroll
    for (int mt = 0; mt < 4; ++mt)
      af[mt] = *(const bf16x8*)&As[(wm * 64 + mt * 16 + fr) * 32 + quad * 8];
#pragma unroll
    for (int nt = 0; nt < 4; ++nt)
      bfr[nt] = *(const bf16x8*)&Bs[(wn * 64 + nt * 16 + fr) * 32 + quad * 8];
#pragma unroll
    for (int mt = 0; mt < 4; ++mt)
#pragma unroll
      for (int nt = 0; nt < 4; ++nt)
        acc[mt][nt] = __builtin_amdgcn_mfma_f32_16x16x32_bf16(
            af[mt], bfr[nt], acc[mt][nt], 0, 0, 0);
  }

  float alpha = (EPI == 5) ? (float)(bf16_t)alpha_p[0] : 0.0f;
  bf16_t* Cb = (bf16_t*)Cv;
  float*  Cf = (float*)Cv;

#pragma unroll
  for (int mt = 0; mt < 4; ++mt) {
#pragma unroll
    for (int nt = 0; nt < 4; ++nt) {
      int ccol = col0 + wn * 64 + nt * 16 + fr;
      float bv = (float)(bf16_t)bias[ccol];
#pragma unroll
      for (int r = 0; r < 4; ++r) {
        int crow = row0 + wm * 64 + mt * 16 + quad * 4 + r;
        size_t idx = (size_t)crow * ldc + ccol;
        float v = acc[mt][nt][r] + bv;
        if (EPI == 1) {
          v = v > 0.0f ? v : 0.0f;
          Cb[idx] = (bf16_t)v;
        } else if (EPI == 2) {
          v += (float)Cb[idx];
          Cb[idx] = (bf16_t)v;
        } else if (EPI == 3) {            // C=A_q ; out2 = A_q*(q+sumq)
          bf16_t a = (bf16_t)v;
          Cb[idx] = a;
          float hid = (float)a * ((float)x1[idx] + (float)x2[idx]);
          out2[idx] = (bf16_t)hid;
        } else if (EPI == 4) {            // C = (relu(v)+sumh+resqh)*Dh
          float h = (float)(bf16_t)(v > 0.0f ? v : 0.0f);
          float u = (h + (float)x1[idx] + (float)x2[idx]) * (float)x3[idx];
          Cb[idx] = (bf16_t)u;
        } else if (EPI == 5) {            // qn = qold - leaky(v); out2=qn*resS
          float z = v >= 0.0f ? v : alpha * v;
          float qn = (float)Cb[idx] - z;
          bf16_t qb = (bf16_t)qn;
          Cb[idx] = qb;
          out2[idx] = (bf16_t)((float)qb * (float)x1[idx]);
        } else {
          if (OUTF32) Cf[idx] = v; else Cb[idx] = (bf16_t)v;
        }
      }
    }
  }
}

enum { E_NONE = 0, E_RELU, E_ACC, E_AQHID, E_UFUSE, E_QUPD };

static inline void gemm(int epi, bool f32out, const bf16_t* A, int lda,
                        const bf16_t* W, int K, const float* bias, void* C,
                        int M, const bf16_t* x1, const bf16_t* x2,
                        const bf16_t* x3, bf16_t* out2, const float* alpha,
                        hipStream_t s) {
  dim3 grid(M / 128, NS / 128), blk(256);
  if (f32out) {
    gemm_nt<E_NONE, true><<<grid, blk, 0, s>>>(A, lda, W, K, bias, C, M, x1, x2, x3, out2, alpha);
    return;
  }
  switch (epi) {
    case E_NONE:  gemm_nt<E_NONE,  false><<<grid, blk, 0, s>>>(A, lda, W, K, bias, C, M, x1, x2, x3, out2, alpha); break;
    case E_RELU:  gemm_nt<E_RELU,  false><<<grid, blk, 0, s>>>(A, lda, W, K, bias, C, M, x1, x2, x3, out2, alpha); break;
    case E_ACC:   gemm_nt<E_ACC,   false><<<grid, blk, 0, s>>>(A, lda, W, K, bias, C, M, x1, x2, x3, out2, alpha); break;
    case E_AQHID: gemm_nt<E_AQHID, false><<<grid, blk, 0, s>>>(A, lda, W, K, bias, C, M, x1, x2, x3, out2, alpha); break;
    case E_UFUSE: gemm_nt<E_UFUSE, false><<<grid, blk, 0, s>>>(A, lda, W, K, bias, C, M, x1, x2, x3, out2, alpha); break;
    case E_QUPD:  gemm_nt<E_QUPD,  false><<<grid, blk, 0, s>>>(A, lda, W, K, bias, C, M, x1, x2, x3, out2, alpha); break;
  }
}

extern "C" void kernel_launch(void* const* d_in, const int* in_sizes, int n_in,
                              void* d_out, int out_size, void* d_ws,
                              size_t ws_size, hipStream_t stream) {
  const float* x      = (const float*)d_in[0];
  const float* b_h0q  = (const float*)d_in[2];
  const float* b_sq   = (const float*)d_in[4];
  const float* b_h0h  = (const float*)d_in[6];
  const float* b_S    = (const float*)d_in[8];
  const float* b_q0h  = (const float*)d_in[10];
  const float* bb_Aq  = (const float*)d_in[12];
  const float* bb_Dh  = (const float*)d_in[14];
  const float* bb_fh  = (const float*)d_in[16];
  const float* bb_hf  = (const float*)d_in[18];
  const float* a_hf   = (const float*)d_in[19];
  const float* bb_rq  = (const float*)d_in[21];
  const float* b_out  = (const float*)d_in[23];
  float* out = (float*)d_out;

  // weight sources: W_S, W_sq, W_h0q, W_h0h, W_q0h, Wb_Aq, Wb_Dh, Wb_fh,
  //                 Wb_hf, Wb_resq, W_out
  const float* wsrc[11] = {(const float*)d_in[7],  (const float*)d_in[3],
                           (const float*)d_in[1],  (const float*)d_in[5],
                           (const float*)d_in[9],  (const float*)d_in[11],
                           (const float*)d_in[13], (const float*)d_in[15],
                           (const float*)d_in[17], (const float*)d_in[20],
                           (const float*)d_in[22]};
  const size_t wper[11] = {4194304, 2097152, 131072, 65536, 2097152,
                           4194304, 2097152, 2097152, 2097152, 2097152,
                           4194304};
  const int wcnt[11] = {1, 1, 1, 1, 1, 6, 6, 6, 6, 6, 1};

  size_t wtot = 0;
  for (int i = 0; i < 11; ++i) wtot += wper[i] * wcnt[i];   // 88,276,992

  const size_t base_elems = XE + 4 * NF + 4 * NH;           // 126,353,408
  const size_t need_rot   = (base_elems + 4194304) * 2;
  const size_t need_full  = (base_elems + wtot) * 2;
  const bool full = ws_size >= need_full;
  if (!full && ws_size < need_rot) return;   // fail loudly

  bf16_t* wsb = (bf16_t*)d_ws;
  size_t off = 0;
  auto alloc = [&](size_t n) { bf16_t* p = wsb + off; off += n; return p; };

  bf16_t* xb    = alloc(XE);
  bf16_t* q     = alloc(NF);
  bf16_t* resS  = alloc(NF);
  bf16_t* sumq  = alloc(NF);
  bf16_t* Aq    = alloc(NF);
  bf16_t* resqh = alloc(NH);
  bf16_t* sumh  = alloc(NH);
  bf16_t* tH1   = alloc(NH);
  bf16_t* tH2   = alloc(NH);
  bf16_t* tF1   = (bf16_t*)d_out;        // d_out (NF fp32) = 2 NF bf16 buffers
  bf16_t* tF2   = tF1 + NF;

  auto cvt = [&](const float* src, bf16_t* dst, size_t n) {
    cvt_w<<<(int)(n / 2048), 256, 0, stream>>>(src, dst);
  };

  bf16_t* wb[11];
  bf16_t* wrot = nullptr;
  if (full) {
    for (int i = 0; i < 11; ++i) {
      wb[i] = alloc(wper[i] * wcnt[i]);
      cvt(wsrc[i], wb[i], wper[i] * wcnt[i]);
    }
  } else {
    wrot = alloc(4194304);
  }
  auto WW = [&](int i, int b) -> const bf16_t* {
    if (full) return wb[i] + (size_t)b * wper[i];
    cvt(wsrc[i] + (size_t)b * wper[i], wrot, wper[i]);
    return wrot;
  };

  cvt(x, xb, XE);
  ew_qinit<<<(int)(NF / 2048), 256, 0, stream>>>(x, q);

  // res_S_q = relu(d @ W_S^T + b_S)
  gemm(E_RELU, false, xb + HDIM + B0DIM, XCOLS, WW(0, 0), FDIM, b_S, resS, FDIM,
       nullptr, nullptr, nullptr, nullptr, nullptr, stream);
  // sum_q_const = s @ W_sq^T + b_sq ; += h0 @ W_h0q^T + b_h0q
  gemm(E_NONE, false, xb, XCOLS, WW(1, 0), HDIM, b_sq, sumq, FDIM,
       nullptr, nullptr, nullptr, nullptr, nullptr, stream);
  gemm(E_ACC, false, xb + HDIM, XCOLS, WW(2, 0), B0DIM, b_h0q, sumq, FDIM,
       nullptr, nullptr, nullptr, nullptr, nullptr, stream);
  // sum_h_const = h0 @ W_h0h^T + b_h0h
  gemm(E_NONE, false, xb + HDIM, XCOLS, WW(3, 0), B0DIM, b_h0h, sumh, HDIM,
       nullptr, nullptr, nullptr, nullptr, nullptr, stream);
  // res_q_h = q @ W_q0h^T + b_q0h  (no relu)
  gemm(E_NONE, false, q, FDIM, WW(4, 0), FDIM, b_q0h, resqh, HDIM,
       nullptr, nullptr, nullptr, nullptr, nullptr, stream);
  // tF1 = q * res_S_q
  ew_mul<<<(int)(NF / 2048), 256, 0, stream>>>(q, resS, tF1);

  for (int b = 0; b < NBLK; ++b) {
    // A_q = tF1 @ W_Aq^T + b ; tF2 = A_q*(q+sumq)   [fused]
    gemm(E_AQHID, false, tF1, FDIM, WW(5, b), FDIM, bb_Aq + b * FDIM, Aq, FDIM,
         q, sumq, nullptr, tF2, nullptr, stream);
    // D_h = relu(A_q @ W_Dh^T + b)
    gemm(E_RELU, false, Aq, FDIM, WW(6, b), FDIM, bb_Dh + b * HDIM, tH1, HDIM,
         nullptr, nullptr, nullptr, nullptr, nullptr, stream);
    // u = (relu(tF2 @ W_fh^T + b) + sumh + resqh) * D_h   [fused]
    gemm(E_UFUSE, false, tF2, FDIM, WW(7, b), FDIM, bb_fh + b * HDIM, tH2, HDIM,
         sumh, resqh, tH1, nullptr, nullptr, stream);
    // q = q - leaky(u @ W_hf^T + b, a[b]) ; tF1 = q_new*resS   [fused]
    gemm(E_QUPD, false, tH2, HDIM, WW(8, b), HDIM, bb_hf + b * FDIM, q, FDIM,
         resS, nullptr, nullptr, tF1, a_hf + b, stream);
    // res_q_h = relu(q @ W_resq^T + b)
    gemm(E_RELU, false, q, FDIM, WW(9, b), FDIM, bb_rq + b * HDIM, resqh, HDIM,
         nullptr, nullptr, nullptr, nullptr, nullptr, stream);
  }

  // out = q @ W_out^T + b_out  (fp32)
  gemm(E_NONE, true, q, FDIM, WW(10, 0), FDIM, b_out, out, ODIM,
       nullptr, nullptr, nullptr, nullptr, nullptr, stream);
}